// Round 9
// baseline (306.126 us; speedup 1.0000x reference)
//
#include <hip/hip_runtime.h>
#include <math.h>

#define NBLK 256
#define HB   32      // histogram blocks (range-partitioned)
#define HT   1024    // threads per histogram block
#define RMAX 3200    // max bins per histogram block (N/HB = 3125)

typedef __attribute__((ext_vector_type(8))) short short8v;  // 8 bf16 (4 VGPR)
typedef __attribute__((ext_vector_type(4))) float f32x4;

__device__ __forceinline__ unsigned cvt_pk_bf16(float lo, float hi) {
    unsigned r;
    asm("v_cvt_pk_bf16_f32 %0, %1, %2" : "=v"(r) : "v"(lo), "v"(hi));
    return r;
}
__device__ __forceinline__ float bf_lo(unsigned u) { return __uint_as_float(u << 16); }
__device__ __forceinline__ float bf_hi(unsigned u) { return __uint_as_float(u & 0xffff0000u); }

__device__ __forceinline__ float fast_tanh(float x) {
    float cx = fminf(fmaxf(x, -15.f), 15.f);
    float e = __expf(2.f * cx);
    return (e - 1.f) / (e + 1.f);
}

// ---------- CSR build: range-partitioned LDS histogram (no global atomics) ----------

__global__ __launch_bounds__(HT) void count_hist_k(const int* __restrict__ dst, int E,
                                                   int* __restrict__ cnt, int n, int R) {
    __shared__ int hist[RMAX];
    const int base = blockIdx.x * R;
    for (int j = threadIdx.x; j < R; j += HT) hist[j] = 0;
    __syncthreads();
    const int e4 = E >> 2;
    const int4* d4 = (const int4*)dst;
    for (int i = threadIdx.x; i < e4; i += HT) {
        int4 d = d4[i];
        int v;
        v = d.x - base; if ((unsigned)v < (unsigned)R) atomicAdd(&hist[v], 1);
        v = d.y - base; if ((unsigned)v < (unsigned)R) atomicAdd(&hist[v], 1);
        v = d.z - base; if ((unsigned)v < (unsigned)R) atomicAdd(&hist[v], 1);
        v = d.w - base; if ((unsigned)v < (unsigned)R) atomicAdd(&hist[v], 1);
    }
    for (int e = (e4 << 2) + threadIdx.x; e < E; e += HT) {
        int v = dst[e] - base; if ((unsigned)v < (unsigned)R) atomicAdd(&hist[v], 1);
    }
    __syncthreads();
    for (int j = threadIdx.x; j < R; j += HT) {
        int b = base + j;
        if (b < n) cnt[b] = hist[j];
    }
}

__global__ __launch_bounds__(HT) void fill_hist_k(const int* __restrict__ src, const int* __restrict__ dst,
                                                  int E, const int* __restrict__ off,
                                                  int* __restrict__ srcs, int n, int R) {
    __shared__ int cur[RMAX];
    const int base = blockIdx.x * R;
    for (int j = threadIdx.x; j < R; j += HT) {
        int b = base + j;
        cur[j] = (b < n) ? off[b] : 0;
    }
    __syncthreads();
    const int e4 = E >> 2;
    const int4* d4 = (const int4*)dst;
    const int4* s4 = (const int4*)src;
    for (int i = threadIdx.x; i < e4; i += HT) {
        int4 d = d4[i];
        int4 s = s4[i];
        int v;
        v = d.x - base; if ((unsigned)v < (unsigned)R) srcs[atomicAdd(&cur[v], 1)] = s.x;
        v = d.y - base; if ((unsigned)v < (unsigned)R) srcs[atomicAdd(&cur[v], 1)] = s.y;
        v = d.z - base; if ((unsigned)v < (unsigned)R) srcs[atomicAdd(&cur[v], 1)] = s.z;
        v = d.w - base; if ((unsigned)v < (unsigned)R) srcs[atomicAdd(&cur[v], 1)] = s.w;
    }
    for (int e = (e4 << 2) + threadIdx.x; e < E; e += HT) {
        int v = dst[e] - base;
        if ((unsigned)v < (unsigned)R) srcs[atomicAdd(&cur[v], 1)] = src[e];
    }
}

// ---------- scan (exclusive prefix over cnt -> off) ----------

__global__ __launch_bounds__(NBLK) void scan1_k(const int* __restrict__ cnt, int n,
                                                int* __restrict__ off, int* __restrict__ bsum) {
    __shared__ int ls[NBLK];
    int base = blockIdx.x * 1024 + threadIdx.x * 4;
    int v[4]; int s = 0;
#pragma unroll
    for (int i = 0; i < 4; ++i) {
        int idx = base + i;
        v[i] = (idx < n) ? cnt[idx] : 0;
        s += v[i];
    }
    ls[threadIdx.x] = s;
    __syncthreads();
    for (int o = 1; o < NBLK; o <<= 1) {
        int t = (threadIdx.x >= (unsigned)o) ? ls[threadIdx.x - o] : 0;
        __syncthreads();
        ls[threadIdx.x] += t;
        __syncthreads();
    }
    int run = ls[threadIdx.x] - s;
#pragma unroll
    for (int i = 0; i < 4; ++i) {
        int idx = base + i;
        if (idx < n) off[idx] = run;
        run += v[i];
    }
    if (threadIdx.x == NBLK - 1) bsum[blockIdx.x] = ls[NBLK - 1];
}

__global__ void scan2_k(int* bsum, int nb) {
    __shared__ int ls[128];
    int t = threadIdx.x;
    int v = (t < nb) ? bsum[t] : 0;
    ls[t] = v;
    __syncthreads();
    for (int o = 1; o < 128; o <<= 1) {
        int tv = (t >= o) ? ls[t - o] : 0;
        __syncthreads();
        ls[t] += tv;
        __syncthreads();
    }
    if (t < nb) bsum[t] = ls[t] - v;
}

__global__ __launch_bounds__(NBLK) void scan3_k(int* __restrict__ off, const int* __restrict__ bsum,
                                                const int* __restrict__ cnt,
                                                float* __restrict__ dinv, int n) {
    int i = blockIdx.x * blockDim.x + threadIdx.x;
    if (i < n) {
        off[i] += bsum[i >> 10];
        dinv[i] = rsqrtf((float)(cnt[i] + 1));   // deg includes self-loop
    }
}

// cast + transpose both weight matrices: Wt[col][k] bf16 (128x128 each)
__global__ __launch_bounds__(NBLK) void wcast_k(const float* __restrict__ W1, const float* __restrict__ W2,
                                                ushort* __restrict__ Wt1, ushort* __restrict__ Wt2) {
    int i = blockIdx.x * blockDim.x + threadIdx.x;   // 0..32767
    int which = i >> 14;
    int idx = i & 16383;
    const float* W = which ? W2 : W1;
    ushort* Wt = which ? Wt2 : Wt1;
    int k = idx >> 7, c = idx & 127;
    float v = W[idx];
    Wt[c * 128 + k] = (ushort)(cvt_pk_bf16(v, v) & 0xffffu);
}

// ---------- GEMM v3: Gb(bf16) = [dinv[row] *] (Xin @ W) via MFMA 16x16x32 bf16 ----------
// block 256 = 4 waves, one 64-row tile per block. W staged in XOR-swizzled LDS (32KB only).
// A-frags loaded DIRECTLY from global (layout row=lane&15, k=(lane>>4)*8+j is 4x b128 /
// 8x float4+cvt per lane) — issued BEFORE the W barrier so HBM latency hides under staging.
// One __syncthreads total; 4 blocks/CU.

template<int CVT, int DINV>
__global__ __launch_bounds__(NBLK, 4) void gemm_mfma_k(const void* __restrict__ Xin,
                                                       const ushort* __restrict__ Wt,
                                                       const float* __restrict__ dinv,
                                                       ushort* __restrict__ Gb, int nrows) {
    __shared__ unsigned Wls[128 * 64];   // 32KB: 128 cols x 16 units(8 bf16), swizzled
    const int t = threadIdx.x;
    const int lane = t & 63;
    const int wv = t >> 6;
    const int l15 = lane & 15;
    const int g = lane >> 4;
    const int row0 = blockIdx.x * 64;

    // stage W: 2048 uint4 units, linear global -> swizzled LDS
    {
        const uint4* Wv = (const uint4*)Wt;
        for (int i = t; i < 2048; i += NBLK) {
            int col = i >> 4, ku = i & 15;
            *(uint4*)&Wls[(col * 16 + (ku ^ (col & 15))) * 4] = Wv[i];
        }
    }

    // A-frags direct from global (overlaps W staging latency)
    int arow = row0 + wv * 16 + l15;
    int ar = (arow < nrows) ? arow : 0;
    short8v A[4];
    if (CVT) {
        const float4* Xv = (const float4*)Xin;
#pragma unroll
        for (int ks = 0; ks < 4; ++ks) {
            float4 f0 = Xv[(size_t)ar * 32 + ks * 8 + g * 2];
            float4 f1 = Xv[(size_t)ar * 32 + ks * 8 + g * 2 + 1];
            union { uint4 u; short8v s; } c;
            c.u.x = cvt_pk_bf16(f0.x, f0.y); c.u.y = cvt_pk_bf16(f0.z, f0.w);
            c.u.z = cvt_pk_bf16(f1.x, f1.y); c.u.w = cvt_pk_bf16(f1.z, f1.w);
            A[ks] = c.s;
        }
    } else {
        const uint4* Xu = (const uint4*)Xin;
#pragma unroll
        for (int ks = 0; ks < 4; ++ks) {
            union { uint4 u; short8v s; } c;
            c.u = Xu[(size_t)ar * 16 + ks * 4 + g];
            A[ks] = c.s;
        }
    }

    __syncthreads();   // W staged

    f32x4 acc[8];
#pragma unroll
    for (int nt = 0; nt < 8; ++nt) acc[nt] = (f32x4){0.f, 0.f, 0.f, 0.f};
#pragma unroll
    for (int nt = 0; nt < 8; ++nt) {
        int col = nt * 16 + l15;
#pragma unroll
        for (int ks = 0; ks < 4; ++ks) {
            int ku = ks * 4 + g;
            short8v b = *(short8v*)&Wls[(col * 16 + (ku ^ (col & 15))) * 4];
            acc[nt] = __builtin_amdgcn_mfma_f32_16x16x32_bf16(A[ks], b, acc[nt], 0, 0, 0);
        }
    }

    int trow0 = row0 + wv * 16;
    float dv[4];
#pragma unroll
    for (int q = 0; q < 4; ++q) {
        int row = trow0 + g * 4 + q;
        dv[q] = DINV ? ((row < nrows) ? dinv[row] : 0.f) : 1.f;
    }
#pragma unroll
    for (int nt = 0; nt < 8; ++nt)
#pragma unroll
        for (int q = 0; q < 4; ++q) {
            int row = trow0 + g * 4 + q;
            if (row < nrows) {
                float val = DINV ? acc[nt][q] * dv[q] : acc[nt][q];
                Gb[(size_t)row * 128 + nt * 16 + l15] =
                    (ushort)(cvt_pk_bf16(val, val) & 0xffffu);
            }
        }
}

// ---------- aggregate (bf16 gather) ----------
// out[n] = dinv[n] * ( w_self*g[n] + sum_{e: dst=n} w_e*g[src] ) + b, opt tanh.
// SRC_DINV: w = dinv[src] (layer 1: g rows unscaled); else w = 1 (g rows prescaled).
// 4 nodes/wave, 16 lanes/node; lane il owns uint4 unit il -> one full 256B row per instruction.
// unroll x8 -> 8 rows in flight; tail slots gather own row (L1-hot) with weight 0.

#define UPK_FMA(u4, nm, A) { \
    A[0] = fmaf(bf_lo((u4).x), (nm), A[0]); A[1] = fmaf(bf_hi((u4).x), (nm), A[1]); \
    A[2] = fmaf(bf_lo((u4).y), (nm), A[2]); A[3] = fmaf(bf_hi((u4).y), (nm), A[3]); \
    A[4] = fmaf(bf_lo((u4).z), (nm), A[4]); A[5] = fmaf(bf_hi((u4).z), (nm), A[5]); \
    A[6] = fmaf(bf_lo((u4).w), (nm), A[6]); A[7] = fmaf(bf_hi((u4).w), (nm), A[7]); }

template<int SRC_DINV, int TANH_, int OUT_BF16>
__global__ __launch_bounds__(NBLK, 4) void aggregate_k(const ushort* __restrict__ Gb,
                                                       const int* __restrict__ off, const int* __restrict__ deg_,
                                                       const int* __restrict__ srcs,
                                                       const float* __restrict__ dinv,
                                                       const float* __restrict__ bias,
                                                       void* __restrict__ outp, int n) {
    int node = (blockIdx.x * blockDim.x + threadIdx.x) >> 4;
    if (node >= n) return;
    int il = threadIdx.x & 15;

    const uint4* Gv = (const uint4*)Gb;   // 16 uint4 per row
    float dvn = dinv[node];
    float sw = SRC_DINV ? dvn : 1.f;
    uint4 s0 = Gv[(size_t)node * 16 + il];
    float acc[8] = {
        bf_lo(s0.x) * sw, bf_hi(s0.x) * sw, bf_lo(s0.y) * sw, bf_hi(s0.y) * sw,
        bf_lo(s0.z) * sw, bf_hi(s0.z) * sw, bf_lo(s0.w) * sw, bf_hi(s0.w) * sw
    };

    int e0 = off[node];
    int deg = deg_[node];
    for (int b = 0; b < deg; b += 8) {
        int sidx[8]; float nm[8];
#pragma unroll
        for (int q = 0; q < 8; ++q) {
            bool v = (b + q) < deg;
            sidx[q] = v ? srcs[e0 + b + q] : node;   // invalid -> own row (L1-hot)
            nm[q] = v ? 1.f : 0.f;
        }
        if (SRC_DINV) {
#pragma unroll
            for (int q = 0; q < 8; ++q) nm[q] *= dinv[sidx[q]];   // 400KB table, L2-resident
        }
        uint4 gr[8];
#pragma unroll
        for (int q = 0; q < 8; ++q) gr[q] = Gv[(size_t)sidx[q] * 16 + il];
#pragma unroll
        for (int q = 0; q < 8; ++q) UPK_FMA(gr[q], nm[q], acc);
    }

    float4 b0 = *(const float4*)&bias[il * 8];
    float4 b1 = *(const float4*)&bias[il * 8 + 4];
    float r[8];
    r[0] = fmaf(acc[0], dvn, b0.x); r[1] = fmaf(acc[1], dvn, b0.y);
    r[2] = fmaf(acc[2], dvn, b0.z); r[3] = fmaf(acc[3], dvn, b0.w);
    r[4] = fmaf(acc[4], dvn, b1.x); r[5] = fmaf(acc[5], dvn, b1.y);
    r[6] = fmaf(acc[6], dvn, b1.z); r[7] = fmaf(acc[7], dvn, b1.w);

    if (TANH_) {
#pragma unroll
        for (int i = 0; i < 8; ++i) r[i] = fast_tanh(r[i]);
    }

    if (OUT_BF16) {
        uint4 o;
        o.x = cvt_pk_bf16(r[0], r[1]); o.y = cvt_pk_bf16(r[2], r[3]);
        o.z = cvt_pk_bf16(r[4], r[5]); o.w = cvt_pk_bf16(r[6], r[7]);
        ((uint4*)outp)[(size_t)node * 16 + il] = o;
    } else {
        float* O = (float*)outp;
        *(float4*)&O[(size_t)node * 128 + il * 8]     = make_float4(r[0], r[1], r[2], r[3]);
        *(float4*)&O[(size_t)node * 128 + il * 8 + 4] = make_float4(r[4], r[5], r[6], r[7]);
    }
}

// ---------- launch ----------

extern "C" void kernel_launch(void* const* d_in, const int* in_sizes, int n_in,
                              void* d_out, int out_size, void* d_ws, size_t ws_size,
                              hipStream_t stream) {
    const float* x  = (const float*)d_in[0];
    const float* W1 = (const float*)d_in[1];
    const float* b1 = (const float*)d_in[2];
    const float* W2 = (const float*)d_in[3];
    const float* b2 = (const float*)d_in[4];
    const int*   ei = (const int*)d_in[5];

    const int N = in_sizes[0] / 128;
    const int E = in_sizes[5] / 2;
    const int* src = ei;
    const int* dst = ei + E;

    char* p = (char*)d_ws;
    ushort* gb    = (ushort*)p; p += (size_t)N * 128 * sizeof(ushort);   // bf16 h (layer1) / g2 (layer2)
    ushort* tb    = (ushort*)p; p += (size_t)N * 128 * sizeof(ushort);   // bf16 layer-1 activation
    int*    cnt   = (int*)p;    p += (size_t)N * sizeof(int);            // deg (histogram output)
    int*    off   = (int*)p;    p += (size_t)N * sizeof(int);
    float*  dinv  = (float*)p;  p += (size_t)N * sizeof(float);
    int*    srcs  = (int*)p;    p += (size_t)E * sizeof(int);
    ushort* Wt1   = (ushort*)p; p += 16384 * sizeof(ushort);
    ushort* Wt2   = (ushort*)p; p += 16384 * sizeof(ushort);
    int*    bsum  = (int*)p;    p += 1024;

    const int nb  = (N + 1023) / 1024;
    const int nbt = (N + 63) / 64;
    const int R   = (N + HB - 1) / HB;                            // bins per histogram block
    const int agg_blocks = ((size_t)N * 16 + NBLK - 1) / NBLK;    // 16 lanes/node

    wcast_k<<<128, NBLK, 0, stream>>>(W1, W2, Wt1, Wt2);

    // layer-1 GEMM (pure; no dinv, no count)
    gemm_mfma_k<1, 0><<<nbt, NBLK, 0, stream>>>(x, Wt1, nullptr, gb, N);

    // CSR build: LDS histogram -> scan -> LDS-cursor fill (no global atomics)
    count_hist_k<<<HB, HT, 0, stream>>>(dst, E, cnt, N, R);
    scan1_k<<<nb, NBLK, 0, stream>>>(cnt, N, off, bsum);
    scan2_k<<<1, 128, 0, stream>>>(bsum, nb);
    scan3_k<<<(N + NBLK - 1) / NBLK, NBLK, 0, stream>>>(off, bsum, cnt, dinv, N);
    fill_hist_k<<<HB, HT, 0, stream>>>(src, dst, E, off, srcs, N, R);

    // layer-1 aggregate: per-src dinv, tanh, bf16 out
    aggregate_k<1, 1, 1><<<agg_blocks, NBLK, 0, stream>>>(gb, off, cnt, srcs, dinv, b1, tb, N);
    // layer-2 GEMM: g2 = dinv * (tb @ W2)
    gemm_mfma_k<0, 1><<<nbt, NBLK, 0, stream>>>(tb, Wt2, dinv, gb, N);
    // layer-2 aggregate: prescaled rows, f32 out
    aggregate_k<0, 0, 0><<<agg_blocks, NBLK, 0, stream>>>(gb, off, cnt, srcs, dinv, b2, d_out, N);
}

// Round 10
// 157.799 us; speedup vs baseline: 1.9400x; 1.9400x over previous
//
#include <hip/hip_runtime.h>
#include <math.h>

#define NBLK 256

typedef __attribute__((ext_vector_type(8))) short short8v;  // 8 bf16 (4 VGPR)
typedef __attribute__((ext_vector_type(4))) float f32x4;

__device__ __forceinline__ unsigned cvt_pk_bf16(float lo, float hi) {
    unsigned r;
    asm("v_cvt_pk_bf16_f32 %0, %1, %2" : "=v"(r) : "v"(lo), "v"(hi));
    return r;
}
__device__ __forceinline__ float bf_lo(unsigned u) { return __uint_as_float(u << 16); }
__device__ __forceinline__ float bf_hi(unsigned u) { return __uint_as_float(u & 0xffff0000u); }

__device__ __forceinline__ float fast_tanh(float x) {
    float cx = fminf(fmaxf(x, -15.f), 15.f);
    float e = __expf(2.f * cx);
    return (e - 1.f) / (e + 1.f);
}

// ---------- CSR build ----------

// count: 1 thread/edge, device atomic, record position within bucket.
__global__ __launch_bounds__(NBLK) void count_k(const int* __restrict__ dst, int E,
                                                int* __restrict__ cnt, int* __restrict__ pos) {
    int e = blockIdx.x * blockDim.x + threadIdx.x;
    if (e < E) pos[e] = atomicAdd(&cnt[dst[e]], 1);
}

// atomic-free fill using recorded positions.
__global__ __launch_bounds__(NBLK) void fill2_k(const int* __restrict__ src, const int* __restrict__ dst, int E,
                                                const int* __restrict__ off, const int* __restrict__ pos,
                                                int* __restrict__ srcs) {
    int e = blockIdx.x * blockDim.x + threadIdx.x;
    if (e >= E) return;
    srcs[off[dst[e]] + pos[e]] = src[e];
}

// ---------- scan (exclusive prefix over cnt -> off) ----------

__global__ __launch_bounds__(NBLK) void scan1_k(const int* __restrict__ cnt, int n,
                                                int* __restrict__ off, int* __restrict__ bsum) {
    __shared__ int ls[NBLK];
    int base = blockIdx.x * 1024 + threadIdx.x * 4;
    int v[4]; int s = 0;
#pragma unroll
    for (int i = 0; i < 4; ++i) {
        int idx = base + i;
        v[i] = (idx < n) ? cnt[idx] : 0;
        s += v[i];
    }
    ls[threadIdx.x] = s;
    __syncthreads();
    for (int o = 1; o < NBLK; o <<= 1) {
        int t = (threadIdx.x >= (unsigned)o) ? ls[threadIdx.x - o] : 0;
        __syncthreads();
        ls[threadIdx.x] += t;
        __syncthreads();
    }
    int run = ls[threadIdx.x] - s;
#pragma unroll
    for (int i = 0; i < 4; ++i) {
        int idx = base + i;
        if (idx < n) off[idx] = run;
        run += v[i];
    }
    if (threadIdx.x == NBLK - 1) bsum[blockIdx.x] = ls[NBLK - 1];
}

__global__ void scan2_k(int* bsum, int nb) {
    __shared__ int ls[128];
    int t = threadIdx.x;
    int v = (t < nb) ? bsum[t] : 0;
    ls[t] = v;
    __syncthreads();
    for (int o = 1; o < 128; o <<= 1) {
        int tv = (t >= o) ? ls[t - o] : 0;
        __syncthreads();
        ls[t] += tv;
        __syncthreads();
    }
    if (t < nb) bsum[t] = ls[t] - v;
}

__global__ __launch_bounds__(NBLK) void scan3_k(int* __restrict__ off, const int* __restrict__ bsum,
                                                const int* __restrict__ cnt,
                                                float* __restrict__ dinv, int n) {
    int i = blockIdx.x * blockDim.x + threadIdx.x;
    if (i < n) {
        off[i] += bsum[i >> 10];
        dinv[i] = rsqrtf((float)(cnt[i] + 1));   // deg includes self-loop
    }
}

// cast + transpose both weight matrices: Wt[col][k] bf16 (128x128 each)
__global__ __launch_bounds__(NBLK) void wcast_k(const float* __restrict__ W1, const float* __restrict__ W2,
                                                ushort* __restrict__ Wt1, ushort* __restrict__ Wt2) {
    int i = blockIdx.x * blockDim.x + threadIdx.x;   // 0..32767
    int which = i >> 14;
    int idx = i & 16383;
    const float* W = which ? W2 : W1;
    ushort* Wt = which ? Wt2 : Wt1;
    int k = idx >> 7, c = idx & 127;
    float v = W[idx];
    Wt[c * 128 + k] = (ushort)(cvt_pk_bf16(v, v) & 0xffffu);
}

// ---------- GEMM v3: Gb(bf16) = [dinv[row] *] (Xin @ W) via MFMA 16x16x32 bf16 ----------
// block 256 = 4 waves, one 64-row tile per block. W staged in XOR-swizzled LDS (32KB only).
// A-frags loaded DIRECTLY from global (layout row=lane&15, k=(lane>>4)*8+j is 4x b128 /
// 8x float4+cvt per lane) — issued BEFORE the W barrier so HBM latency hides under staging.
// One __syncthreads total; 4 blocks/CU.

template<int CVT, int DINV>
__global__ __launch_bounds__(NBLK, 4) void gemm_mfma_k(const void* __restrict__ Xin,
                                                       const ushort* __restrict__ Wt,
                                                       const float* __restrict__ dinv,
                                                       ushort* __restrict__ Gb, int nrows) {
    __shared__ unsigned Wls[128 * 64];   // 32KB: 128 cols x 16 units(8 bf16), swizzled
    const int t = threadIdx.x;
    const int lane = t & 63;
    const int wv = t >> 6;
    const int l15 = lane & 15;
    const int g = lane >> 4;
    const int row0 = blockIdx.x * 64;

    // stage W: 2048 uint4 units, linear global -> swizzled LDS
    {
        const uint4* Wv = (const uint4*)Wt;
        for (int i = t; i < 2048; i += NBLK) {
            int col = i >> 4, ku = i & 15;
            *(uint4*)&Wls[(col * 16 + (ku ^ (col & 15))) * 4] = Wv[i];
        }
    }

    // A-frags direct from global (overlaps W staging latency)
    int arow = row0 + wv * 16 + l15;
    int ar = (arow < nrows) ? arow : 0;
    short8v A[4];
    if (CVT) {
        const float4* Xv = (const float4*)Xin;
#pragma unroll
        for (int ks = 0; ks < 4; ++ks) {
            float4 f0 = Xv[(size_t)ar * 32 + ks * 8 + g * 2];
            float4 f1 = Xv[(size_t)ar * 32 + ks * 8 + g * 2 + 1];
            union { uint4 u; short8v s; } c;
            c.u.x = cvt_pk_bf16(f0.x, f0.y); c.u.y = cvt_pk_bf16(f0.z, f0.w);
            c.u.z = cvt_pk_bf16(f1.x, f1.y); c.u.w = cvt_pk_bf16(f1.z, f1.w);
            A[ks] = c.s;
        }
    } else {
        const uint4* Xu = (const uint4*)Xin;
#pragma unroll
        for (int ks = 0; ks < 4; ++ks) {
            union { uint4 u; short8v s; } c;
            c.u = Xu[(size_t)ar * 16 + ks * 4 + g];
            A[ks] = c.s;
        }
    }

    __syncthreads();   // W staged

    f32x4 acc[8];
#pragma unroll
    for (int nt = 0; nt < 8; ++nt) acc[nt] = (f32x4){0.f, 0.f, 0.f, 0.f};
#pragma unroll
    for (int nt = 0; nt < 8; ++nt) {
        int col = nt * 16 + l15;
#pragma unroll
        for (int ks = 0; ks < 4; ++ks) {
            int ku = ks * 4 + g;
            short8v b = *(short8v*)&Wls[(col * 16 + (ku ^ (col & 15))) * 4];
            acc[nt] = __builtin_amdgcn_mfma_f32_16x16x32_bf16(A[ks], b, acc[nt], 0, 0, 0);
        }
    }

    int trow0 = row0 + wv * 16;
    float dv[4];
#pragma unroll
    for (int q = 0; q < 4; ++q) {
        int row = trow0 + g * 4 + q;
        dv[q] = DINV ? ((row < nrows) ? dinv[row] : 0.f) : 1.f;
    }
#pragma unroll
    for (int nt = 0; nt < 8; ++nt)
#pragma unroll
        for (int q = 0; q < 4; ++q) {
            int row = trow0 + g * 4 + q;
            if (row < nrows) {
                float val = DINV ? acc[nt][q] * dv[q] : acc[nt][q];
                Gb[(size_t)row * 128 + nt * 16 + l15] =
                    (ushort)(cvt_pk_bf16(val, val) & 0xffffu);
            }
        }
}

// ---------- aggregate (bf16 gather) ----------
// out[n] = dinv[n] * ( w_self*g[n] + sum_{e: dst=n} w_e*g[src] ) + b, opt tanh.
// SRC_DINV: w = dinv[src] (layer 1: g rows unscaled); else w = 1 (g rows prescaled).
// 4 nodes/wave, 16 lanes/node; lane il owns uint4 unit il -> one full 256B row per instruction.
// unroll x8 -> 8 rows in flight; tail slots gather own row (L1-hot) with weight 0.

#define UPK_FMA(u4, nm, A) { \
    A[0] = fmaf(bf_lo((u4).x), (nm), A[0]); A[1] = fmaf(bf_hi((u4).x), (nm), A[1]); \
    A[2] = fmaf(bf_lo((u4).y), (nm), A[2]); A[3] = fmaf(bf_hi((u4).y), (nm), A[3]); \
    A[4] = fmaf(bf_lo((u4).z), (nm), A[4]); A[5] = fmaf(bf_hi((u4).z), (nm), A[5]); \
    A[6] = fmaf(bf_lo((u4).w), (nm), A[6]); A[7] = fmaf(bf_hi((u4).w), (nm), A[7]); }

template<int SRC_DINV, int TANH_, int OUT_BF16>
__global__ __launch_bounds__(NBLK, 4) void aggregate_k(const ushort* __restrict__ Gb,
                                                       const int* __restrict__ off, const int* __restrict__ deg_,
                                                       const int* __restrict__ srcs,
                                                       const float* __restrict__ dinv,
                                                       const float* __restrict__ bias,
                                                       void* __restrict__ outp, int n) {
    int node = (blockIdx.x * blockDim.x + threadIdx.x) >> 4;
    if (node >= n) return;
    int il = threadIdx.x & 15;

    const uint4* Gv = (const uint4*)Gb;   // 16 uint4 per row
    float dvn = dinv[node];
    float sw = SRC_DINV ? dvn : 1.f;
    uint4 s0 = Gv[(size_t)node * 16 + il];
    float acc[8] = {
        bf_lo(s0.x) * sw, bf_hi(s0.x) * sw, bf_lo(s0.y) * sw, bf_hi(s0.y) * sw,
        bf_lo(s0.z) * sw, bf_hi(s0.z) * sw, bf_lo(s0.w) * sw, bf_hi(s0.w) * sw
    };

    int e0 = off[node];
    int deg = deg_[node];
    for (int b = 0; b < deg; b += 8) {
        int sidx[8]; float nm[8];
#pragma unroll
        for (int q = 0; q < 8; ++q) {
            bool v = (b + q) < deg;
            sidx[q] = v ? srcs[e0 + b + q] : node;   // invalid -> own row (L1-hot)
            nm[q] = v ? 1.f : 0.f;
        }
        if (SRC_DINV) {
#pragma unroll
            for (int q = 0; q < 8; ++q) nm[q] *= dinv[sidx[q]];   // 400KB table, L2-resident
        }
        uint4 gr[8];
#pragma unroll
        for (int q = 0; q < 8; ++q) gr[q] = Gv[(size_t)sidx[q] * 16 + il];
#pragma unroll
        for (int q = 0; q < 8; ++q) UPK_FMA(gr[q], nm[q], acc);
    }

    float4 b0 = *(const float4*)&bias[il * 8];
    float4 b1 = *(const float4*)&bias[il * 8 + 4];
    float r[8];
    r[0] = fmaf(acc[0], dvn, b0.x); r[1] = fmaf(acc[1], dvn, b0.y);
    r[2] = fmaf(acc[2], dvn, b0.z); r[3] = fmaf(acc[3], dvn, b0.w);
    r[4] = fmaf(acc[4], dvn, b1.x); r[5] = fmaf(acc[5], dvn, b1.y);
    r[6] = fmaf(acc[6], dvn, b1.z); r[7] = fmaf(acc[7], dvn, b1.w);

    if (TANH_) {
#pragma unroll
        for (int i = 0; i < 8; ++i) r[i] = fast_tanh(r[i]);
    }

    if (OUT_BF16) {
        uint4 o;
        o.x = cvt_pk_bf16(r[0], r[1]); o.y = cvt_pk_bf16(r[2], r[3]);
        o.z = cvt_pk_bf16(r[4], r[5]); o.w = cvt_pk_bf16(r[6], r[7]);
        ((uint4*)outp)[(size_t)node * 16 + il] = o;
    } else {
        float* O = (float*)outp;
        *(float4*)&O[(size_t)node * 128 + il * 8]     = make_float4(r[0], r[1], r[2], r[3]);
        *(float4*)&O[(size_t)node * 128 + il * 8 + 4] = make_float4(r[4], r[5], r[6], r[7]);
    }
}

// ---------- launch ----------

extern "C" void kernel_launch(void* const* d_in, const int* in_sizes, int n_in,
                              void* d_out, int out_size, void* d_ws, size_t ws_size,
                              hipStream_t stream) {
    const float* x  = (const float*)d_in[0];
    const float* W1 = (const float*)d_in[1];
    const float* b1 = (const float*)d_in[2];
    const float* W2 = (const float*)d_in[3];
    const float* b2 = (const float*)d_in[4];
    const int*   ei = (const int*)d_in[5];

    const int N = in_sizes[0] / 128;
    const int E = in_sizes[5] / 2;
    const int* src = ei;
    const int* dst = ei + E;

    char* p = (char*)d_ws;
    ushort* gb    = (ushort*)p; p += (size_t)N * 128 * sizeof(ushort);   // bf16 h (layer1) / g2 (layer2)
    ushort* tb    = (ushort*)p; p += (size_t)N * 128 * sizeof(ushort);   // bf16 layer-1 activation
    int*    cnt   = (int*)p;    p += (size_t)N * sizeof(int);            // deg
    int*    off   = (int*)p;    p += (size_t)N * sizeof(int);
    float*  dinv  = (float*)p;  p += (size_t)N * sizeof(float);
    int*    srcs  = (int*)p;    p += (size_t)E * sizeof(int);
    int*    pos   = (int*)p;    p += (size_t)E * sizeof(int);
    ushort* Wt1   = (ushort*)p; p += 16384 * sizeof(ushort);
    ushort* Wt2   = (ushort*)p; p += 16384 * sizeof(ushort);
    int*    bsum  = (int*)p;    p += 1024;

    const int nb  = (N + 1023) / 1024;
    const int nbt = (N + 63) / 64;
    const int agg_blocks = ((size_t)N * 16 + NBLK - 1) / NBLK;    // 16 lanes/node

    hipMemsetAsync(cnt, 0, (size_t)N * sizeof(int), stream);
    wcast_k<<<128, NBLK, 0, stream>>>(W1, W2, Wt1, Wt2);

    // CSR build: atomic count (+pos) -> scan -> atomic-free fill
    count_k<<<(E + NBLK - 1) / NBLK, NBLK, 0, stream>>>(dst, E, cnt, pos);

    // layer-1 GEMM (pure) — independent of CSR, placed here to keep count/scan latency visible
    gemm_mfma_k<1, 0><<<nbt, NBLK, 0, stream>>>(x, Wt1, nullptr, gb, N);

    scan1_k<<<nb, NBLK, 0, stream>>>(cnt, N, off, bsum);
    scan2_k<<<1, 128, 0, stream>>>(bsum, nb);
    scan3_k<<<(N + NBLK - 1) / NBLK, NBLK, 0, stream>>>(off, bsum, cnt, dinv, N);
    fill2_k<<<(E + NBLK - 1) / NBLK, NBLK, 0, stream>>>(src, dst, E, off, pos, srcs);

    // layer-1 aggregate: per-src dinv, tanh, bf16 out
    aggregate_k<1, 1, 1><<<agg_blocks, NBLK, 0, stream>>>(gb, off, cnt, srcs, dinv, b1, tb, N);
    // layer-2 GEMM: g2 = dinv * (tb @ W2)
    gemm_mfma_k<0, 1><<<nbt, NBLK, 0, stream>>>(tb, Wt2, dinv, gb, N);
    // layer-2 aggregate: prescaled rows, f32 out
    aggregate_k<0, 0, 0><<<agg_blocks, NBLK, 0, stream>>>(gb, off, cnt, srcs, dinv, b2, d_out, N);
}

// Round 11
// 154.781 us; speedup vs baseline: 1.9778x; 1.0195x over previous
//
#include <hip/hip_runtime.h>
#include <math.h>

#define NBLK 256

typedef __attribute__((ext_vector_type(8))) short short8v;  // 8 bf16 (4 VGPR)
typedef __attribute__((ext_vector_type(4))) float f32x4;

__device__ __forceinline__ unsigned cvt_pk_bf16(float lo, float hi) {
    unsigned r;
    asm("v_cvt_pk_bf16_f32 %0, %1, %2" : "=v"(r) : "v"(lo), "v"(hi));
    return r;
}
__device__ __forceinline__ float bf_lo(unsigned u) { return __uint_as_float(u << 16); }
__device__ __forceinline__ float bf_hi(unsigned u) { return __uint_as_float(u & 0xffff0000u); }

__device__ __forceinline__ float fast_tanh(float x) {
    float cx = fminf(fmaxf(x, -15.f), 15.f);
    float e = __expf(2.f * cx);
    return (e - 1.f) / (e + 1.f);
}

// ---------- CSR build ----------

// count: 1 thread/edge, device atomic, record position within bucket.
__global__ __launch_bounds__(NBLK) void count_k(const int* __restrict__ dst, int E,
                                                int* __restrict__ cnt, int* __restrict__ pos) {
    int e = blockIdx.x * blockDim.x + threadIdx.x;
    if (e < E) pos[e] = atomicAdd(&cnt[dst[e]], 1);
}

// atomic-free fill using recorded positions; off finalized on the fly (+bsum).
__global__ __launch_bounds__(NBLK) void fill2_k(const int* __restrict__ src, const int* __restrict__ dst, int E,
                                                const int* __restrict__ off, const int* __restrict__ bsum,
                                                const int* __restrict__ pos, int* __restrict__ srcs) {
    int e = blockIdx.x * blockDim.x + threadIdx.x;
    if (e >= E) return;
    int d = dst[e];
    srcs[off[d] + bsum[d >> 10] + pos[e]] = src[e];
}

// ---------- scan (exclusive prefix over cnt -> off, block-local; bsum = block totals) ----------
// also emits dinv (deg available here).

__global__ __launch_bounds__(NBLK) void scan1_k(const int* __restrict__ cnt, int n,
                                                int* __restrict__ off, int* __restrict__ bsum,
                                                float* __restrict__ dinv) {
    __shared__ int ls[NBLK];
    int base = blockIdx.x * 1024 + threadIdx.x * 4;
    int v[4]; int s = 0;
#pragma unroll
    for (int i = 0; i < 4; ++i) {
        int idx = base + i;
        v[i] = (idx < n) ? cnt[idx] : 0;
        s += v[i];
    }
    ls[threadIdx.x] = s;
    __syncthreads();
    for (int o = 1; o < NBLK; o <<= 1) {
        int t = (threadIdx.x >= (unsigned)o) ? ls[threadIdx.x - o] : 0;
        __syncthreads();
        ls[threadIdx.x] += t;
        __syncthreads();
    }
    int run = ls[threadIdx.x] - s;
#pragma unroll
    for (int i = 0; i < 4; ++i) {
        int idx = base + i;
        if (idx < n) {
            off[idx] = run;                              // block-local exclusive prefix
            dinv[idx] = rsqrtf((float)(v[i] + 1));       // deg includes self-loop
        }
        run += v[i];
    }
    if (threadIdx.x == NBLK - 1) bsum[blockIdx.x] = ls[NBLK - 1];
}

__global__ void scan2_k(int* bsum, int nb) {
    __shared__ int ls[128];
    int t = threadIdx.x;
    int v = (t < nb) ? bsum[t] : 0;
    ls[t] = v;
    __syncthreads();
    for (int o = 1; o < 128; o <<= 1) {
        int tv = (t >= o) ? ls[t - o] : 0;
        __syncthreads();
        ls[t] += tv;
        __syncthreads();
    }
    if (t < nb) bsum[t] = ls[t] - v;   // exclusive block bases
}

// cast + transpose both weight matrices: Wt[col][k] bf16 (128x128 each); also zero cnt.
__global__ __launch_bounds__(NBLK) void wcast_k(const float* __restrict__ W1, const float* __restrict__ W2,
                                                ushort* __restrict__ Wt1, ushort* __restrict__ Wt2,
                                                int* __restrict__ cnt, int n) {
    int i = blockIdx.x * blockDim.x + threadIdx.x;   // 0..32767
    for (int j = i; j < n; j += 32768) cnt[j] = 0;
    int which = i >> 14;
    int idx = i & 16383;
    const float* W = which ? W2 : W1;
    ushort* Wt = which ? Wt2 : Wt1;
    int k = idx >> 7, c = idx & 127;
    float v = W[idx];
    Wt[c * 128 + k] = (ushort)(cvt_pk_bf16(v, v) & 0xffffu);
}

// ---------- GEMM v3: Gb(bf16) = [dinv[row] *] (Xin @ W) via MFMA 16x16x32 bf16 ----------
// block 256 = 4 waves, one 64-row tile per block. W staged in XOR-swizzled LDS (32KB only).
// A-frags loaded DIRECTLY from global — issued BEFORE the W barrier so HBM latency hides
// under staging. One __syncthreads total; 4 blocks/CU.

template<int CVT, int DINV>
__global__ __launch_bounds__(NBLK, 4) void gemm_mfma_k(const void* __restrict__ Xin,
                                                       const ushort* __restrict__ Wt,
                                                       const float* __restrict__ dinv,
                                                       ushort* __restrict__ Gb, int nrows) {
    __shared__ unsigned Wls[128 * 64];   // 32KB: 128 cols x 16 units(8 bf16), swizzled
    const int t = threadIdx.x;
    const int lane = t & 63;
    const int wv = t >> 6;
    const int l15 = lane & 15;
    const int g = lane >> 4;
    const int row0 = blockIdx.x * 64;

    // stage W: 2048 uint4 units, linear global -> swizzled LDS
    {
        const uint4* Wv = (const uint4*)Wt;
        for (int i = t; i < 2048; i += NBLK) {
            int col = i >> 4, ku = i & 15;
            *(uint4*)&Wls[(col * 16 + (ku ^ (col & 15))) * 4] = Wv[i];
        }
    }

    // A-frags direct from global (overlaps W staging latency)
    int arow = row0 + wv * 16 + l15;
    int ar = (arow < nrows) ? arow : 0;
    short8v A[4];
    if (CVT) {
        const float4* Xv = (const float4*)Xin;
#pragma unroll
        for (int ks = 0; ks < 4; ++ks) {
            float4 f0 = Xv[(size_t)ar * 32 + ks * 8 + g * 2];
            float4 f1 = Xv[(size_t)ar * 32 + ks * 8 + g * 2 + 1];
            union { uint4 u; short8v s; } c;
            c.u.x = cvt_pk_bf16(f0.x, f0.y); c.u.y = cvt_pk_bf16(f0.z, f0.w);
            c.u.z = cvt_pk_bf16(f1.x, f1.y); c.u.w = cvt_pk_bf16(f1.z, f1.w);
            A[ks] = c.s;
        }
    } else {
        const uint4* Xu = (const uint4*)Xin;
#pragma unroll
        for (int ks = 0; ks < 4; ++ks) {
            union { uint4 u; short8v s; } c;
            c.u = Xu[(size_t)ar * 16 + ks * 4 + g];
            A[ks] = c.s;
        }
    }

    __syncthreads();   // W staged

    f32x4 acc[8];
#pragma unroll
    for (int nt = 0; nt < 8; ++nt) acc[nt] = (f32x4){0.f, 0.f, 0.f, 0.f};
#pragma unroll
    for (int nt = 0; nt < 8; ++nt) {
        int col = nt * 16 + l15;
#pragma unroll
        for (int ks = 0; ks < 4; ++ks) {
            int ku = ks * 4 + g;
            short8v b = *(short8v*)&Wls[(col * 16 + (ku ^ (col & 15))) * 4];
            acc[nt] = __builtin_amdgcn_mfma_f32_16x16x32_bf16(A[ks], b, acc[nt], 0, 0, 0);
        }
    }

    int trow0 = row0 + wv * 16;
    float dv[4];
#pragma unroll
    for (int q = 0; q < 4; ++q) {
        int row = trow0 + g * 4 + q;
        dv[q] = DINV ? ((row < nrows) ? dinv[row] : 0.f) : 1.f;
    }
#pragma unroll
    for (int nt = 0; nt < 8; ++nt)
#pragma unroll
        for (int q = 0; q < 4; ++q) {
            int row = trow0 + g * 4 + q;
            if (row < nrows) {
                float val = DINV ? acc[nt][q] * dv[q] : acc[nt][q];
                Gb[(size_t)row * 128 + nt * 16 + l15] =
                    (ushort)(cvt_pk_bf16(val, val) & 0xffffu);
            }
        }
}

// ---------- aggregate (bf16 gather) ----------
// out[n] = dinv[n] * ( w_self*g[n] + sum_{e: dst=n} w_e*g[src] ) + b, opt tanh.
// SRC_DINV: w = dinv[src] (layer 1: g rows unscaled); else w = 1 (g rows prescaled).
// 4 nodes/wave, 16 lanes/node; lane il owns uint4 unit il -> one full 256B row per instruction.
// unroll x8 -> 8 rows in flight; tail slots gather own row (L1-hot) with weight 0.
// off finalized on the fly (+bsum[node>>10], L1-resident 98-entry table).

#define UPK_FMA(u4, nm, A) { \
    A[0] = fmaf(bf_lo((u4).x), (nm), A[0]); A[1] = fmaf(bf_hi((u4).x), (nm), A[1]); \
    A[2] = fmaf(bf_lo((u4).y), (nm), A[2]); A[3] = fmaf(bf_hi((u4).y), (nm), A[3]); \
    A[4] = fmaf(bf_lo((u4).z), (nm), A[4]); A[5] = fmaf(bf_hi((u4).z), (nm), A[5]); \
    A[6] = fmaf(bf_lo((u4).w), (nm), A[6]); A[7] = fmaf(bf_hi((u4).w), (nm), A[7]); }

template<int SRC_DINV, int TANH_, int OUT_BF16>
__global__ __launch_bounds__(NBLK, 4) void aggregate_k(const ushort* __restrict__ Gb,
                                                       const int* __restrict__ off, const int* __restrict__ bsum,
                                                       const int* __restrict__ deg_,
                                                       const int* __restrict__ srcs,
                                                       const float* __restrict__ dinv,
                                                       const float* __restrict__ bias,
                                                       void* __restrict__ outp, int n) {
    int node = (blockIdx.x * blockDim.x + threadIdx.x) >> 4;
    if (node >= n) return;
    int il = threadIdx.x & 15;

    const uint4* Gv = (const uint4*)Gb;   // 16 uint4 per row
    float dvn = dinv[node];
    float sw = SRC_DINV ? dvn : 1.f;
    uint4 s0 = Gv[(size_t)node * 16 + il];
    float acc[8] = {
        bf_lo(s0.x) * sw, bf_hi(s0.x) * sw, bf_lo(s0.y) * sw, bf_hi(s0.y) * sw,
        bf_lo(s0.z) * sw, bf_hi(s0.z) * sw, bf_lo(s0.w) * sw, bf_hi(s0.w) * sw
    };

    int e0 = off[node] + bsum[node >> 10];
    int deg = deg_[node];
    for (int b = 0; b < deg; b += 8) {
        int sidx[8]; float nm[8];
#pragma unroll
        for (int q = 0; q < 8; ++q) {
            bool v = (b + q) < deg;
            sidx[q] = v ? srcs[e0 + b + q] : node;   // invalid -> own row (L1-hot)
            nm[q] = v ? 1.f : 0.f;
        }
        if (SRC_DINV) {
#pragma unroll
            for (int q = 0; q < 8; ++q) nm[q] *= dinv[sidx[q]];   // 400KB table, L2-resident
        }
        uint4 gr[8];
#pragma unroll
        for (int q = 0; q < 8; ++q) gr[q] = Gv[(size_t)sidx[q] * 16 + il];
#pragma unroll
        for (int q = 0; q < 8; ++q) UPK_FMA(gr[q], nm[q], acc);
    }

    float4 b0 = *(const float4*)&bias[il * 8];
    float4 b1 = *(const float4*)&bias[il * 8 + 4];
    float r[8];
    r[0] = fmaf(acc[0], dvn, b0.x); r[1] = fmaf(acc[1], dvn, b0.y);
    r[2] = fmaf(acc[2], dvn, b0.z); r[3] = fmaf(acc[3], dvn, b0.w);
    r[4] = fmaf(acc[4], dvn, b1.x); r[5] = fmaf(acc[5], dvn, b1.y);
    r[6] = fmaf(acc[6], dvn, b1.z); r[7] = fmaf(acc[7], dvn, b1.w);

    if (TANH_) {
#pragma unroll
        for (int i = 0; i < 8; ++i) r[i] = fast_tanh(r[i]);
    }

    if (OUT_BF16) {
        uint4 o;
        o.x = cvt_pk_bf16(r[0], r[1]); o.y = cvt_pk_bf16(r[2], r[3]);
        o.z = cvt_pk_bf16(r[4], r[5]); o.w = cvt_pk_bf16(r[6], r[7]);
        ((uint4*)outp)[(size_t)node * 16 + il] = o;
    } else {
        float* O = (float*)outp;
        *(float4*)&O[(size_t)node * 128 + il * 8]     = make_float4(r[0], r[1], r[2], r[3]);
        *(float4*)&O[(size_t)node * 128 + il * 8 + 4] = make_float4(r[4], r[5], r[6], r[7]);
    }
}

// ---------- launch ----------

extern "C" void kernel_launch(void* const* d_in, const int* in_sizes, int n_in,
                              void* d_out, int out_size, void* d_ws, size_t ws_size,
                              hipStream_t stream) {
    const float* x  = (const float*)d_in[0];
    const float* W1 = (const float*)d_in[1];
    const float* b1 = (const float*)d_in[2];
    const float* W2 = (const float*)d_in[3];
    const float* b2 = (const float*)d_in[4];
    const int*   ei = (const int*)d_in[5];

    const int N = in_sizes[0] / 128;
    const int E = in_sizes[5] / 2;
    const int* src = ei;
    const int* dst = ei + E;

    char* p = (char*)d_ws;
    ushort* gb    = (ushort*)p; p += (size_t)N * 128 * sizeof(ushort);   // bf16 h (layer1) / g2 (layer2)
    ushort* tb    = (ushort*)p; p += (size_t)N * 128 * sizeof(ushort);   // bf16 layer-1 activation
    int*    cnt   = (int*)p;    p += (size_t)N * sizeof(int);            // deg
    int*    off   = (int*)p;    p += (size_t)N * sizeof(int);            // block-local prefix
    float*  dinv  = (float*)p;  p += (size_t)N * sizeof(float);
    int*    srcs  = (int*)p;    p += (size_t)E * sizeof(int);
    int*    pos   = (int*)p;    p += (size_t)E * sizeof(int);
    ushort* Wt1   = (ushort*)p; p += 16384 * sizeof(ushort);
    ushort* Wt2   = (ushort*)p; p += 16384 * sizeof(ushort);
    int*    bsum  = (int*)p;    p += 1024;

    const int nb  = (N + 1023) / 1024;
    const int nbt = (N + 63) / 64;
    const int agg_blocks = ((size_t)N * 16 + NBLK - 1) / NBLK;    // 16 lanes/node

    // weight cast + cnt zeroing (fused)
    wcast_k<<<128, NBLK, 0, stream>>>(W1, W2, Wt1, Wt2, cnt, N);

    // CSR build: atomic count (+pos) -> scan (2 kernels, emits dinv) -> atomic-free fill
    count_k<<<(E + NBLK - 1) / NBLK, NBLK, 0, stream>>>(dst, E, cnt, pos);

    // layer-1 GEMM (pure) — independent of CSR
    gemm_mfma_k<1, 0><<<nbt, NBLK, 0, stream>>>(x, Wt1, nullptr, gb, N);

    scan1_k<<<nb, NBLK, 0, stream>>>(cnt, N, off, bsum, dinv);
    scan2_k<<<1, 128, 0, stream>>>(bsum, nb);
    fill2_k<<<(E + NBLK - 1) / NBLK, NBLK, 0, stream>>>(src, dst, E, off, bsum, pos, srcs);

    // layer-1 aggregate: per-src dinv, tanh, bf16 out
    aggregate_k<1, 1, 1><<<agg_blocks, NBLK, 0, stream>>>(gb, off, bsum, cnt, srcs, dinv, b1, tb, N);
    // layer-2 GEMM: g2 = dinv * (tb @ W2)
    gemm_mfma_k<0, 1><<<nbt, NBLK, 0, stream>>>(tb, Wt2, dinv, gb, N);
    // layer-2 aggregate: prescaled rows, f32 out
    aggregate_k<0, 0, 0><<<agg_blocks, NBLK, 0, stream>>>(gb, off, bsum, cnt, srcs, dinv, b2, d_out, N);
}